// Round 11
// baseline (175.622 us; speedup 1.0000x reference)
//
#include <hip/hip_runtime.h>
#include <hip/hip_fp16.h>
#include <math.h>

typedef _Float16 f16;
typedef __attribute__((ext_vector_type(8))) _Float16 f16x8;
typedef __attribute__((ext_vector_type(4))) _Float16 f16x4;
typedef __attribute__((ext_vector_type(4))) float f32x4;
typedef unsigned int u32;

#define NB 16
#define NN 2048
#define ND 256
#define KVB 32
#define QB 64
#define XSZ ((size_t)NB * NN * ND)   // 8388608 elements

__device__ __forceinline__ void gll16(const void* g, void* l) {
    __builtin_amdgcn_global_load_lds(
        (const __attribute__((address_space(1))) unsigned int*)g,
        (__attribute__((address_space(3))) unsigned int*)l, 16, 0, 0);
}

__device__ __forceinline__ long long len_at(const int* lenp, int b, bool is64) {
    return is64 ? ((const long long*)lenp)[b] : (long long)lenp[b];
}

__device__ __forceinline__ float bperm_f(int src_lane, float v) {
    return __int_as_float(__builtin_amdgcn_ds_bpermute(src_lane * 4, __float_as_int(v)));
}

// ---------------- pre-pass: X fp32 -> Xh f16 [b][n][d] + Xt f16 [b][d][n] ----
__global__ __launch_bounds__(256)
void prep(const float* __restrict__ X, f16* __restrict__ Xh, f16* __restrict__ Xt)
{
    const int b  = blockIdx.z;
    const int n0 = blockIdx.x * 64;
    const int d0 = blockIdx.y * 64;
    const int t  = threadIdx.x;
    __shared__ f16 T[64][72];

    const float* Xb  = X  + ((size_t)b*NN + n0)*ND + d0;
    f16*         Xhb = Xh + ((size_t)b*NN + n0)*ND + d0;
    #pragma unroll
    for (int it = 0; it < 4; ++it) {
        int r  = it*16 + (t >> 4);
        int c4 = t & 15;
        float4 v = *(const float4*)(Xb + (size_t)r*ND + c4*4);
        f16x4 h; h[0]=(f16)v.x; h[1]=(f16)v.y; h[2]=(f16)v.z; h[3]=(f16)v.w;
        *(f16x4*)&Xhb[(size_t)r*ND + c4*4] = h;
        *(f16x4*)&T[r][c4*4] = h;
    }
    __syncthreads();
    f16* Xtb = Xt + ((size_t)b*ND + d0)*NN + n0;
    #pragma unroll
    for (int it = 0; it < 2; ++it) {
        int id = it*256 + t;
        int dr = id >> 3;
        int ch = id & 7;
        f16x8 v;
        #pragma unroll
        for (int u = 0; u < 8; ++u) v[u] = T[ch*8+u][dr];
        *(f16x8*)&Xtb[(size_t)dr*NN + ch*8] = v;
    }
}

// ---------------- attn10: attn8 + 32KB LDS (5 blocks/CU) + snake-LPT --------
// Identical math/pipeline to attn8 (swapped-QK in-lane softmax, split-KV x2,
// 3-barrier single-buffer). Changes:
//  * P repack C-layout -> A-frag via 8 ds_bpermute + cndmask (no Pl buffer)
//    -> LDS exactly 32KB -> 5 blocks/CU.
//  * snake-LPT: CU slot s gets job ranks {s, 511-s, 512+s, 1023-s} over the
//    length-sorted job list -> per-CU work ~constant.
__global__ __launch_bounds__(256, 4)
void attn10(const f16* __restrict__ Xh, const f16* __restrict__ Xt,
            const int* __restrict__ lenp,
            f16* __restrict__ Op, float* __restrict__ Sl)
{
    const int tid  = threadIdx.x;
    const int lane = tid & 63;
    const int w = tid >> 6;
    const int g = lane >> 4;
    const int c = lane & 15;

    // ---- snake-LPT job mapping over length-sorted job list ----
    const bool is64 = (lenp[1] == 0);
    long long Lv[NB];
    #pragma unroll
    for (int i = 0; i < NB; ++i) Lv[i] = len_at(lenp, i, is64);
    const int i  = blockIdx.x;            // 0..1023
    const int rr = i >> 8;                // round 0..3
    const int ss = i & 255;               // CU slot signature (8c+x)
    const int rank = rr*256 + ((rr & 1) ? (255 - ss) : ss);
    const int brk = rank >> 6;            // batch rank 0..15 (sorted desc)
    const int qt  = (rank >> 1) & 31;
    const int h   = rank & 1;             // KV half (tile parity)
    int bsel = 0; long long Lb = 1;
    #pragma unroll
    for (int bb = 0; bb < NB; ++bb) {
        int rk = 0;
        #pragma unroll
        for (int b2 = 0; b2 < NB; ++b2)
            rk += (Lv[b2] > Lv[bb]) || (Lv[b2] == Lv[bb] && b2 < bb);
        if (rk == brk) { bsel = bb; Lb = Lv[bb]; }
    }
    const int nt  = (int)((Lb + KVB - 1) / KVB);
    const int nth = (h == 0) ? ((nt + 1) >> 1) : (nt >> 1);
    if (nth == 0) return;

    __shared__ f16 Kl[8192];        // 16KB
    __shared__ f16 Vl[8192];        // 16KB  -> total exactly 32KB

    const char* xhb = (const char*)(Xh + (size_t)bsel*NN*ND);
    const char* xtb = (const char*)(Xt + (size_t)bsel*ND*NN);

    // ---- Q fragments (B-operand of swapped QK) ----
    f16x8 qf[8];
    {
        const char* qp = xhb + (size_t)(qt*QB + w*16 + c)*512 + g*16;
        #pragma unroll
        for (int kk = 0; kk < 8; ++kk) qf[kk] = *(const f16x8*)(qp + kk*64);
    }

    auto stage_k = [&](int kv0) {
        char* kb = (char*)&Kl[0];
        #pragma unroll
        for (int it = 0; it < 4; ++it) {
            int S  = it*256 + tid;
            int kk = S >> 7, j = (S >> 2) & 31, gg = S & 3;
            gll16(xhb + (size_t)(kv0 + j)*512 + kk*64 + gg*16, kb + S*16);
        }
    };
    auto stage_v = [&](int kv0) {
        char* vb = (char*)&Vl[0];
        #pragma unroll
        for (int it = 0; it < 4; ++it) {
            int T  = it*256 + tid;
            int dt = T >> 6, cc = (T >> 2) & 15, gg = T & 3;
            gll16(xtb + (size_t)(dt*16 + cc)*4096 + (size_t)(kv0 + gg*8)*2, vb + T*16);
        }
    };

    f32x4 o[16];
    #pragma unroll
    for (int dt = 0; dt < 16; ++dt) o[dt] = (f32x4){0.f,0.f,0.f,0.f};
    float m = -INFINITY;
    float l = 0.f;

    stage_k(h*KVB);
    stage_v(h*KVB);

    for (int ti = 0; ti < nth; ++ti) {
        const int kv0 = (2*ti + h) * KVB;
        const bool more = (ti + 1 < nth);

        asm volatile("s_waitcnt vmcnt(4)" ::: "memory");   // own K(t) landed
        __builtin_amdgcn_s_barrier();                      // K ready block-wide

        const char* kb = (const char*)&Kl[0];
        const char* vb = (const char*)&Vl[0];

        // ---- QK^T swapped: lane (c,g) reg r = S[q=c][j=4g+r | 16+4g+r] ----
        f32x4 s0 = (f32x4){0.f,0.f,0.f,0.f};
        f32x4 s1 = (f32x4){0.f,0.f,0.f,0.f};
        __builtin_amdgcn_s_setprio(1);
        #pragma unroll
        for (int kk = 0; kk < 8; ++kk) {
            f16x8 b0 = *(const f16x8*)(kb + kk*2048        + c*64 + g*16);
            f16x8 b1 = *(const f16x8*)(kb + kk*2048 + 1024 + c*64 + g*16);
            s0 = __builtin_amdgcn_mfma_f32_16x16x32_f16(b0, qf[kk], s0, 0, 0, 0);
            s1 = __builtin_amdgcn_mfma_f32_16x16x32_f16(b1, qf[kk], s1, 0, 0, 0);
        }
        __builtin_amdgcn_s_setprio(0);

        asm volatile("s_waitcnt vmcnt(0)" ::: "memory");   // own V(t) landed
        __builtin_amdgcn_s_barrier();                      // V ready + K fully read
        if (more) stage_k(kv0 + 2*KVB);                    // overwrite K under SM/PV

        // ---- column mask: j = kv0 + 4g + r (s0), +16 (s1) ----
        const float NEG = -1e30f;
        if (kv0 + KVB > (int)Lb) {
            const int jb = kv0 + g*4;
            #pragma unroll
            for (int r = 0; r < 4; ++r) {
                if (jb + r >= Lb)      s0[r] = NEG;
                if (jb + 16 + r >= Lb) s1[r] = NEG;
            }
        }

        // ---- online softmax, row q=c: in-lane + 2 shuffles ----
        float tm = fmaxf(fmaxf(fmaxf(s0[0],s0[1]), fmaxf(s0[2],s0[3])),
                         fmaxf(fmaxf(s1[0],s1[1]), fmaxf(s1[2],s1[3])));
        tm = fmaxf(tm, __shfl_xor(tm, 16, 64));
        tm = fmaxf(tm, __shfl_xor(tm, 32, 64));
        if (__any(tm > m + 8.f)) {           // defer-max THR=8
            float mn = fmaxf(m, tm);
            float sc = __expf(m - mn);
            m = mn; l *= sc;
            float scr[4];
            #pragma unroll
            for (int r = 0; r < 4; ++r) scr[r] = bperm_f(g*4 + r, sc);
            #pragma unroll
            for (int dt = 0; dt < 16; ++dt) {
                o[dt][0]*=scr[0]; o[dt][1]*=scr[1]; o[dt][2]*=scr[2]; o[dt][3]*=scr[3];
            }
        }
        float p0[4], p1[4];
        #pragma unroll
        for (int r = 0; r < 4; ++r) {
            p0[r] = __expf(s0[r] - m);
            p1[r] = __expf(s1[r] - m);
        }
        float rs = ((p0[0]+p0[1]) + (p0[2]+p0[3])) + ((p1[0]+p1[1]) + (p1[2]+p1[3]));
        rs += __shfl_xor(rs, 16, 64);
        rs += __shfl_xor(rs, 32, 64);
        l += rs;

        // ---- P repack via bpermute: lane (c,g) <- P[q=c][j=8g..8g+7] ----
        // g<2: p0-quads of lanes {2g*16+c, (2g+1)*16+c}
        // g>=2: p1-quads of lanes {(2g-4)*16+c, (2g-3)*16+c}
        f16x4 pa, pb;
        pa[0]=(f16)p0[0]; pa[1]=(f16)p0[1]; pa[2]=(f16)p0[2]; pa[3]=(f16)p0[3];
        pb[0]=(f16)p1[0]; pb[1]=(f16)p1[1]; pb[2]=(f16)p1[2]; pb[3]=(f16)p1[3];
        u32 a0 = ((u32*)&pa)[0], a1 = ((u32*)&pa)[1];
        u32 b0_ = ((u32*)&pb)[0], b1_ = ((u32*)&pb)[1];
        const bool lo = (g < 2);
        const int gA   = lo ? (2*g) : (2*g - 4);
        const int adrA = (gA*16 + c) * 4;
        const int adrB = adrA + 64;
        u32 xA0 = __builtin_amdgcn_ds_bpermute(adrA, a0);
        u32 xA1 = __builtin_amdgcn_ds_bpermute(adrA, a1);
        u32 yA0 = __builtin_amdgcn_ds_bpermute(adrA, b0_);
        u32 yA1 = __builtin_amdgcn_ds_bpermute(adrA, b1_);
        u32 xB0 = __builtin_amdgcn_ds_bpermute(adrB, a0);
        u32 xB1 = __builtin_amdgcn_ds_bpermute(adrB, a1);
        u32 yB0 = __builtin_amdgcn_ds_bpermute(adrB, b0_);
        u32 yB1 = __builtin_amdgcn_ds_bpermute(adrB, b1_);
        union { u32 u[4]; f16x8 v; } pf;
        pf.u[0] = lo ? xA0 : yA0;
        pf.u[1] = lo ? xA1 : yA1;
        pf.u[2] = lo ? xB0 : yB0;
        pf.u[3] = lo ? xB1 : yB1;

        // ---- PV: O[16q x 256d] += P(16x32) x V(32x16) per d-tile ----
        __builtin_amdgcn_s_setprio(1);
        #pragma unroll
        for (int dt = 0; dt < 16; ++dt) {
            f16x8 vf = *(const f16x8*)(vb + dt*1024 + c*64 + g*16);
            o[dt] = __builtin_amdgcn_mfma_f32_16x16x32_f16(pf.v, vf, o[dt], 0, 0, 0);
        }
        __builtin_amdgcn_s_setprio(0);

        asm volatile("" ::: "memory");
        __builtin_amdgcn_s_barrier();                      // all done reading V(t)
        if (more) stage_v(kv0 + 2*KVB);
    }

    // ---- epilogue: normalized partial (f16) + per-row logsumexp (f32) ----
    float linv = 1.f / l;
    float inv[4];
    #pragma unroll
    for (int r = 0; r < 4; ++r) inv[r] = bperm_f(g*4 + r, linv);
    f16* op = Op + (size_t)h*XSZ + ((size_t)bsel*NN + (size_t)(qt*QB + w*16 + g*4))*ND + c;
    #pragma unroll
    for (int r = 0; r < 4; ++r) {
        #pragma unroll
        for (int dt = 0; dt < 16; ++dt)
            op[(size_t)r*ND + dt*16] = (f16)(o[dt][r] * inv[r]);
    }
    if (g == 0) {
        Sl[((size_t)(h*NB + bsel))*NN + (size_t)(qt*QB + w*16 + c)] = m + __logf(l);
    }
}

// ---------------- merge: out = (O1 w1 + O2 w2) / (w1 + w2) ------------------
__global__ __launch_bounds__(256)
void merge(const f16* __restrict__ Op, const float* __restrict__ Sl,
           const int* __restrict__ lenp, float* __restrict__ out)
{
    const int tid = threadIdx.x;
    const int rg  = blockIdx.x * 8 + (tid >> 5);   // global row 0..32767
    const int b   = rg >> 11;
    const int q   = rg & 2047;
    const int d0  = (tid & 31) * 8;

    const bool is64 = (lenp[1] == 0);
    const long long Lb = len_at(lenp, b, is64);

    const f16* p1 = Op + ((size_t)b*NN + q)*ND + d0;
    f16x8 a1 = *(const f16x8*)p1;
    float r[8];
    if (Lb <= KVB) {
        #pragma unroll
        for (int i = 0; i < 8; ++i) r[i] = (float)a1[i];
    } else {
        f16x8 a2 = *(const f16x8*)(p1 + XSZ);
        float s1 = Sl[(size_t)b*NN + q];
        float s2 = Sl[(size_t)(NB + b)*NN + q];
        float sm = fmaxf(s1, s2);
        float w1 = __expf(s1 - sm), w2 = __expf(s2 - sm);
        float dn = 1.f / (w1 + w2);
        w1 *= dn; w2 *= dn;
        #pragma unroll
        for (int i = 0; i < 8; ++i) r[i] = (float)a1[i]*w1 + (float)a2[i]*w2;
    }
    float* ob = out + ((size_t)b*NN + q)*ND + d0;
    *(float4*)ob       = (float4){r[0], r[1], r[2], r[3]};
    *(float4*)(ob + 4) = (float4){r[4], r[5], r[6], r[7]};
}

// ---------------- mid-tier (round-5 attn4, proven) --------------------------
__global__ __launch_bounds__(256, 2)
void attn4(const f16* __restrict__ Xh, const f16* __restrict__ Xt,
           const int* __restrict__ lenp, float* __restrict__ out)
{
    const int tid  = threadIdx.x;
    const int lane = tid & 63;
    const int w = tid >> 6;
    const int g = lane >> 4;
    const int c = lane & 15;

    const bool is64 = (lenp[1] == 0);
    long long Lv[NB];
    #pragma unroll
    for (int i = 0; i < NB; ++i) Lv[i] = len_at(lenp, i, is64);
    const int x = blockIdx.x & 7;
    const int k = blockIdx.x >> 3;
    const int wanted = (k < 32) ? x : (15 - x);
    const int qt = k & 31;
    int bsel = 0; long long Lb = 1;
    #pragma unroll
    for (int bb = 0; bb < NB; ++bb) {
        int rk = 0;
        #pragma unroll
        for (int b2 = 0; b2 < NB; ++b2)
            rk += (Lv[b2] > Lv[bb]) || (Lv[b2] == Lv[bb] && b2 < bb);
        if (rk == wanted) { bsel = bb; Lb = Lv[bb]; }
    }
    const int nt = (int)((Lb + KVB - 1) / KVB);

    __shared__ f16 Kl[2][8192];
    __shared__ f16 Vl[2][8192];
    __shared__ f16 Pl[4][16*36];

    const char* xhb = (const char*)(Xh + (size_t)bsel*NN*ND);
    const char* xtb = (const char*)(Xt + (size_t)bsel*ND*NN);

    f16x8 qf[8];
    {
        const char* qp = xhb + (size_t)(qt*QB + w*16 + c)*512 + g*16;
        #pragma unroll
        for (int kk = 0; kk < 8; ++kk) qf[kk] = *(const f16x8*)(qp + kk*64);
    }

    auto stage = [&](int buf, int kv0) {
        char* kb = (char*)&Kl[buf][0];
        char* vb = (char*)&Vl[buf][0];
        #pragma unroll
        for (int it = 0; it < 4; ++it) {
            int S  = it*256 + tid;
            int kk = S >> 7, j = (S >> 2) & 31, gg = S & 3;
            gll16(xhb + (size_t)(kv0 + j)*512 + kk*64 + gg*16, kb + S*16);
        }
        #pragma unroll
        for (int it = 0; it < 4; ++it) {
            int T  = it*256 + tid;
            int dt = T >> 6, cc = (T >> 2) & 15, gg = T & 3;
            gll16(xtb + (size_t)(dt*16 + cc)*4096 + (size_t)(kv0 + gg*8)*2, vb + T*16);
        }
    };

    f32x4 o[16];
    #pragma unroll
    for (int dt = 0; dt < 16; ++dt) o[dt] = (f32x4){0.f,0.f,0.f,0.f};
    float m[4] = {-INFINITY,-INFINITY,-INFINITY,-INFINITY};
    float l[4] = {0.f,0.f,0.f,0.f};

    f16* pw = &Pl[w][0];

    stage(0, 0);
    if (nt > 1) stage(1, KVB);

    for (int t = 0; t < nt; ++t) {
        const int kv0 = t * KVB;
        const int buf = t & 1;

        if (t + 1 < nt) { asm volatile("s_waitcnt vmcnt(8)" ::: "memory"); }
        else            { asm volatile("s_waitcnt vmcnt(0)" ::: "memory"); }
        __builtin_amdgcn_s_barrier();

        const char* kb = (const char*)&Kl[buf][0];
        const char* vb = (const char*)&Vl[buf][0];

        f32x4 s0 = (f32x4){0.f,0.f,0.f,0.f};
        f32x4 s1 = (f32x4){0.f,0.f,0.f,0.f};
        #pragma unroll
        for (int kk = 0; kk < 8; ++kk) {
            f16x8 b0 = *(const f16x8*)(kb + kk*2048        + c*64 + g*16);
            f16x8 b1 = *(const f16x8*)(kb + kk*2048 + 1024 + c*64 + g*16);
            s0 = __builtin_amdgcn_mfma_f32_16x16x32_f16(qf[kk], b0, s0, 0, 0, 0);
            s1 = __builtin_amdgcn_mfma_f32_16x16x32_f16(qf[kk], b1, s1, 0, 0, 0);
        }

        const float NEG = -1e30f;
        if (kv0 + c >= Lb)      { s0[0]=NEG; s0[1]=NEG; s0[2]=NEG; s0[3]=NEG; }
        if (kv0 + 16 + c >= Lb) { s1[0]=NEG; s1[1]=NEG; s1[2]=NEG; s1[3]=NEG; }

        float mx[4], mn[4], sc[4], p0[4], p1[4], rs[4];
        #pragma unroll
        for (int r = 0; r < 4; ++r) mx[r] = fmaxf(s0[r], s1[r]);
        #pragma unroll
        for (int off = 8; off >= 1; off >>= 1) {
            #pragma unroll
            for (int r = 0; r < 4; ++r)
                mx[r] = fmaxf(mx[r], __shfl_xor(mx[r], off, 64));
        }
        #pragma unroll
        for (int r = 0; r < 4; ++r) {
            mn[r] = fmaxf(m[r], mx[r]);
            sc[r] = __expf(m[r] - mn[r]);
            p0[r] = __expf(s0[r] - mn[r]);
            p1[r] = __expf(s1[r] - mn[r]);
            rs[r] = p0[r] + p1[r];
        }
        #pragma unroll
        for (int off = 8; off >= 1; off >>= 1) {
            #pragma unroll
            for (int r = 0; r < 4; ++r)
                rs[r] += __shfl_xor(rs[r], off, 64);
        }
        bool chg = (sc[0]!=1.f) | (sc[1]!=1.f) | (sc[2]!=1.f) | (sc[3]!=1.f);
        if (__any(chg)) {
            #pragma unroll
            for (int dt = 0; dt < 16; ++dt) {
                o[dt][0]*=sc[0]; o[dt][1]*=sc[1]; o[dt][2]*=sc[2]; o[dt][3]*=sc[3];
            }
        }
        #pragma unroll
        for (int r = 0; r < 4; ++r) { l[r] = l[r]*sc[r] + rs[r]; m[r] = mn[r]; }

        #pragma unroll
        for (int r = 0; r < 4; ++r) {
            pw[(g*4+r)*36 + c]      = (f16)p0[r];
            pw[(g*4+r)*36 + 16 + c] = (f16)p1[r];
        }
        union { f16x4 hh[2]; f16x8 v; } pu;
        pu.hh[0] = *(const f16x4*)(pw + c*36 + g*8);
        pu.hh[1] = *(const f16x4*)(pw + c*36 + g*8 + 4);
        f16x8 pf = pu.v;

        #pragma unroll
        for (int dt = 0; dt < 16; ++dt) {
            f16x8 vf = *(const f16x8*)(vb + dt*1024 + c*64 + g*16);
            o[dt] = __builtin_amdgcn_mfma_f32_16x16x32_f16(pf, vf, o[dt], 0, 0, 0);
        }

        __builtin_amdgcn_s_barrier();
        if (t + 2 < nt) stage(buf, kv0 + 2*KVB);
    }

    float inv[4];
    #pragma unroll
    for (int r = 0; r < 4; ++r) inv[r] = 1.0f / l[r];
    float* ob = out + ((size_t)bsel*NN + (size_t)(qt*QB + w*16 + g*4))*ND + c;
    #pragma unroll
    for (int r = 0; r < 4; ++r) {
        #pragma unroll
        for (int dt = 0; dt < 16; ++dt)
            ob[(size_t)r*ND + dt*16] = o[dt][r] * inv[r];
    }
}

// ---------------- lowest tier (no workspace) --------------------------------
__global__ __launch_bounds__(256, 2)
void attn_fb(const float* __restrict__ X,
             const int* __restrict__ lenp,
             float* __restrict__ out)
{
    const int b   = blockIdx.y;
    const int qt  = blockIdx.x;
    const int tid = threadIdx.x;
    const int lane = tid & 63;
    const int w = tid >> 6;
    const int g = lane >> 4;
    const int c = lane & 15;

    const bool is64 = (lenp[1] == 0);
    const long long Lb = len_at(lenp, b, is64);

    __shared__ f16 Kl[KVB][264];
    __shared__ f16 Vt2[ND][40];
    __shared__ f16 Pl[4][16][40];

    const float* Xb = X + (size_t)b * NN * ND;

    f16x8 qf[8];
    {
        const float* qp = Xb + (size_t)(qt*64 + w*16 + c) * ND + g*8;
        #pragma unroll
        for (int kk = 0; kk < 8; ++kk) {
            float4 a = *(const float4*)(qp + kk*32);
            float4 d = *(const float4*)(qp + kk*32 + 4);
            f16x8 v;
            v[0]=(f16)a.x; v[1]=(f16)a.y; v[2]=(f16)a.z; v[3]=(f16)a.w;
            v[4]=(f16)d.x; v[5]=(f16)d.y; v[6]=(f16)d.z; v[7]=(f16)d.w;
            qf[kk] = v;
        }
    }

    f32x4 o[16];
    #pragma unroll
    for (int dt = 0; dt < 16; ++dt) o[dt] = (f32x4){0.f,0.f,0.f,0.f};
    float m[4] = {-INFINITY,-INFINITY,-INFINITY,-INFINITY};
    float lr[4] = {0.f,0.f,0.f,0.f};

    const int ntiles = (int)((Lb + KVB - 1) / KVB);
    for (int t = 0; t < ntiles; ++t) {
        const int kv0 = t * KVB;
        __syncthreads();
        #pragma unroll
        for (int it = 0; it < 8; ++it) {
            int idx4 = it*256 + tid;
            int row  = idx4 >> 6;
            int c4   = idx4 & 63;
            float4 v = *(const float4*)(Xb + (size_t)(kv0 + row)*ND + c4*4);
            f16x4 hh; hh[0]=(f16)v.x; hh[1]=(f16)v.y; hh[2]=(f16)v.z; hh[3]=(f16)v.w;
            *(f16x4*)&Kl[row][c4*4] = hh;
        }
        {
            const float* cp = Xb + (size_t)kv0*ND + tid;
            #pragma unroll
            for (int kq = 0; kq < 8; ++kq) {
                f16x4 hh;
                #pragma unroll
                for (int u = 0; u < 4; ++u) hh[u] = (f16)cp[(size_t)(kq*4+u)*ND];
                *(f16x4*)&Vt2[tid][kq*4] = hh;
            }
        }
        __syncthreads();

        f32x4 s0 = (f32x4){0.f,0.f,0.f,0.f};
        f32x4 s1 = (f32x4){0.f,0.f,0.f,0.f};
        #pragma unroll
        for (int kk = 0; kk < 8; ++kk) {
            f16x8 b0 = *(const f16x8*)&Kl[c     ][kk*32 + g*8];
            f16x8 b1 = *(const f16x8*)&Kl[16 + c][kk*32 + g*8];
            s0 = __builtin_amdgcn_mfma_f32_16x16x32_f16(qf[kk], b0, s0, 0, 0, 0);
            s1 = __builtin_amdgcn_mfma_f32_16x16x32_f16(qf[kk], b1, s1, 0, 0, 0);
        }

        const float NEG = -1e30f;
        if (kv0 + c >= Lb)      { s0[0]=NEG; s0[1]=NEG; s0[2]=NEG; s0[3]=NEG; }
        if (kv0 + 16 + c >= Lb) { s1[0]=NEG; s1[1]=NEG; s1[2]=NEG; s1[3]=NEG; }

        float mx[4], mn[4], sc[4], p0[4], p1[4], rs[4];
        #pragma unroll
        for (int r = 0; r < 4; ++r) mx[r] = fmaxf(s0[r], s1[r]);
        #pragma unroll
        for (int off = 8; off >= 1; off >>= 1) {
            #pragma unroll
            for (int r = 0; r < 4; ++r)
                mx[r] = fmaxf(mx[r], __shfl_xor(mx[r], off, 64));
        }
        #pragma unroll
        for (int r = 0; r < 4; ++r) {
            mn[r] = fmaxf(m[r], mx[r]);
            sc[r] = __expf(m[r] - mn[r]);
            p0[r] = __expf(s0[r] - mn[r]);
            p1[r] = __expf(s1[r] - mn[r]);
            rs[r] = p0[r] + p1[r];
        }
        #pragma unroll
        for (int off = 8; off >= 1; off >>= 1) {
            #pragma unroll
            for (int r = 0; r < 4; ++r)
                rs[r] += __shfl_xor(rs[r], off, 64);
        }
        bool chg = (sc[0]!=1.f) | (sc[1]!=1.f) | (sc[2]!=1.f) | (sc[3]!=1.f);
        if (__any(chg)) {
            #pragma unroll
            for (int dt = 0; dt < 16; ++dt) {
                o[dt][0]*=sc[0]; o[dt][1]*=sc[1]; o[dt][2]*=sc[2]; o[dt][3]*=sc[3];
            }
        }
        #pragma unroll
        for (int r = 0; r < 4; ++r) { lr[r] = lr[r]*sc[r] + rs[r]; m[r] = mn[r]; }

        #pragma unroll
        for (int r = 0; r < 4; ++r) {
            Pl[w][g*4+r][c]      = (f16)p0[r];
            Pl[w][g*4+r][16 + c] = (f16)p1[r];
        }
        f16x8 pf = *(const f16x8*)&Pl[w][c][g*8];

        #pragma unroll
        for (int dt = 0; dt < 16; ++dt) {
            f16x8 vf = *(const f16x8*)&Vt2[dt*16 + c][g*8];
            o[dt] = __builtin_amdgcn_mfma_f32_16x16x32_f16(pf, vf, o[dt], 0, 0, 0);
        }
    }

    float inv[4];
    #pragma unroll
    for (int r = 0; r < 4; ++r) inv[r] = 1.0f / lr[r];
    float* ob = out + ((size_t)b*NN + (size_t)(qt*64 + w*16 + g*4))*ND + c;
    #pragma unroll
    for (int r = 0; r < 4; ++r) {
        #pragma unroll
        for (int dt = 0; dt < 16; ++dt)
            ob[(size_t)r*ND + dt*16] = o[dt][r] * inv[r];
    }
}

extern "C" void kernel_launch(void* const* d_in, const int* in_sizes, int n_in,
                              void* d_out, int out_size, void* d_ws, size_t ws_size,
                              hipStream_t stream) {
    const float* X    = (const float*)d_in[0];
    const int*   lenp = (const int*)d_in[1];
    float*       out  = (float*)d_out;

    const size_t need_base  = XSZ * 2 * 2;                    // Xh + Xt (f16)
    const size_t need_split = need_base + XSZ * 2 * 2         // + Op[2] (f16)
                              + (size_t)2 * NB * NN * 4;      // + Sl (f32)
    if (ws_size >= need_split) {
        f16* Xh = (f16*)d_ws;
        f16* Xt = Xh + XSZ;
        f16* Op = Xt + XSZ;
        float* Sl = (float*)(Op + 2*XSZ);
        hipLaunchKernelGGL(prep, dim3(NN/64, ND/64, NB), dim3(256), 0, stream, X, Xh, Xt);
        hipLaunchKernelGGL(attn10, dim3(1024), dim3(256), 0, stream, Xh, Xt, lenp, Op, Sl);
        hipLaunchKernelGGL(merge, dim3(NB*NN/8), dim3(256), 0, stream, Op, Sl, lenp, out);
    } else if (ws_size >= need_base) {
        f16* Xh = (f16*)d_ws;
        f16* Xt = Xh + XSZ;
        hipLaunchKernelGGL(prep, dim3(NN/64, ND/64, NB), dim3(256), 0, stream, X, Xh, Xt);
        hipLaunchKernelGGL(attn4, dim3(512), dim3(256), 0, stream, Xh, Xt, lenp, out);
    } else {
        hipLaunchKernelGGL(attn_fb, dim3(NN/64, NB), dim3(256), 0, stream, X, lenp, out);
    }
}

// Round 12
// 96.387 us; speedup vs baseline: 1.8221x; 1.8221x over previous
//
#include <hip/hip_runtime.h>
#include <hip/hip_fp16.h>
#include <math.h>

typedef _Float16 f16;
typedef __attribute__((ext_vector_type(8))) _Float16 f16x8;
typedef __attribute__((ext_vector_type(4))) _Float16 f16x4;
typedef __attribute__((ext_vector_type(4))) float f32x4;
typedef unsigned int u32;

#define NB 16
#define NN 2048
#define ND 256
#define KVB 32
#define QB 64
#define XSZ ((size_t)NB * NN * ND)   // 8388608 elements

__device__ __forceinline__ void gll16(const void* g, void* l) {
    __builtin_amdgcn_global_load_lds(
        (const __attribute__((address_space(1))) unsigned int*)g,
        (__attribute__((address_space(3))) unsigned int*)l, 16, 0, 0);
}

__device__ __forceinline__ long long len_at(const int* lenp, int b, bool is64) {
    return is64 ? ((const long long*)lenp)[b] : (long long)lenp[b];
}

__device__ __forceinline__ float bperm_f(int src_lane, float v) {
    return __int_as_float(__builtin_amdgcn_ds_bpermute(src_lane * 4, __float_as_int(v)));
}

// ---------------- pre-pass: X fp32 -> Xh f16 [b][n][d] + Xt f16 [b][d][n] ----
__global__ __launch_bounds__(256)
void prep(const float* __restrict__ X, f16* __restrict__ Xh, f16* __restrict__ Xt)
{
    const int b  = blockIdx.z;
    const int n0 = blockIdx.x * 64;
    const int d0 = blockIdx.y * 64;
    const int t  = threadIdx.x;
    __shared__ f16 T[64][72];

    const float* Xb  = X  + ((size_t)b*NN + n0)*ND + d0;
    f16*         Xhb = Xh + ((size_t)b*NN + n0)*ND + d0;
    #pragma unroll
    for (int it = 0; it < 4; ++it) {
        int r  = it*16 + (t >> 4);
        int c4 = t & 15;
        float4 v = *(const float4*)(Xb + (size_t)r*ND + c4*4);
        f16x4 h; h[0]=(f16)v.x; h[1]=(f16)v.y; h[2]=(f16)v.z; h[3]=(f16)v.w;
        *(f16x4*)&Xhb[(size_t)r*ND + c4*4] = h;
        *(f16x4*)&T[r][c4*4] = h;
    }
    __syncthreads();
    f16* Xtb = Xt + ((size_t)b*ND + d0)*NN + n0;
    #pragma unroll
    for (int it = 0; it < 2; ++it) {
        int id = it*256 + t;
        int dr = id >> 3;
        int ch = id & 7;
        f16x8 v;
        #pragma unroll
        for (int u = 0; u < 8; ++u) v[u] = T[ch*8+u][dr];
        *(f16x8*)&Xtb[(size_t)dr*NN + ch*8] = v;
    }
}

// ---------------- attn11: attn8 (proven 76us) + snake-LPT job mapping -------
// Swapped-QK in-lane softmax, split-KV x2, 3-barrier single-buffer pipeline,
// LDS P-roundtrip. Only change vs attn8: block -> job mapping is a snake over
// the length-sorted job list so each CU-slot's 4 sequential jobs have
// rank-sum ~ constant (per-CU work equalized).
__global__ __launch_bounds__(256, 2)
void attn11(const f16* __restrict__ Xh, const f16* __restrict__ Xt,
            const int* __restrict__ lenp,
            f16* __restrict__ Op, float* __restrict__ Sl)
{
    const int tid  = threadIdx.x;
    const int lane = tid & 63;
    const int w = tid >> 6;
    const int g = lane >> 4;
    const int c = lane & 15;

    // ---- snake-LPT job mapping over length-sorted job list ----
    const bool is64 = (lenp[1] == 0);
    long long Lv[NB];
    #pragma unroll
    for (int i = 0; i < NB; ++i) Lv[i] = len_at(lenp, i, is64);
    const int i  = blockIdx.x;            // 0..1023
    const int rr = i >> 8;                // round 0..3
    const int ss = i & 255;               // CU-slot signature
    const int rank = rr*256 + ((rr & 1) ? (255 - ss) : ss);
    const int brk = rank >> 6;            // batch rank (sorted desc)
    const int qt  = (rank >> 1) & 31;
    const int h   = rank & 1;             // KV half (tile parity)
    int bsel = 0; long long Lb = 1;
    #pragma unroll
    for (int bb = 0; bb < NB; ++bb) {
        int rk = 0;
        #pragma unroll
        for (int b2 = 0; b2 < NB; ++b2)
            rk += (Lv[b2] > Lv[bb]) || (Lv[b2] == Lv[bb] && b2 < bb);
        if (rk == brk) { bsel = bb; Lb = Lv[bb]; }
    }
    const int nt  = (int)((Lb + KVB - 1) / KVB);
    const int nth = (h == 0) ? ((nt + 1) >> 1) : (nt >> 1);
    if (nth == 0) return;

    __shared__ f16 Kl[8192];        // 16KB single buffer
    __shared__ f16 Vl[8192];        // 16KB single buffer
    __shared__ f16 Pl[4][16*40];    // per-wave P repack, 80B rows

    const char* xhb = (const char*)(Xh + (size_t)bsel*NN*ND);
    const char* xtb = (const char*)(Xt + (size_t)bsel*ND*NN);

    // ---- Q fragments (B-operand of swapped QK) ----
    f16x8 qf[8];
    {
        const char* qp = xhb + (size_t)(qt*QB + w*16 + c)*512 + g*16;
        #pragma unroll
        for (int kk = 0; kk < 8; ++kk) qf[kk] = *(const f16x8*)(qp + kk*64);
    }

    auto stage_k = [&](int kv0) {
        char* kb = (char*)&Kl[0];
        #pragma unroll
        for (int it = 0; it < 4; ++it) {
            int S  = it*256 + tid;
            int kk = S >> 7, j = (S >> 2) & 31, gg = S & 3;
            gll16(xhb + (size_t)(kv0 + j)*512 + kk*64 + gg*16, kb + S*16);
        }
    };
    auto stage_v = [&](int kv0) {
        char* vb = (char*)&Vl[0];
        #pragma unroll
        for (int it = 0; it < 4; ++it) {
            int T  = it*256 + tid;
            int dt = T >> 6, cc = (T >> 2) & 15, gg = T & 3;
            gll16(xtb + (size_t)(dt*16 + cc)*4096 + (size_t)(kv0 + gg*8)*2, vb + T*16);
        }
    };

    f32x4 o[16];
    #pragma unroll
    for (int dt = 0; dt < 16; ++dt) o[dt] = (f32x4){0.f,0.f,0.f,0.f};
    float m = -INFINITY;
    float l = 0.f;

    f16* pw = &Pl[w][0];

    stage_k(h*KVB);
    stage_v(h*KVB);

    for (int ti = 0; ti < nth; ++ti) {
        const int kv0 = (2*ti + h) * KVB;
        const bool more = (ti + 1 < nth);

        asm volatile("s_waitcnt vmcnt(4)" ::: "memory");   // own K(t) landed
        __builtin_amdgcn_s_barrier();                      // K ready block-wide

        const char* kb = (const char*)&Kl[0];
        const char* vb = (const char*)&Vl[0];

        // ---- QK^T swapped: lane (c,g) reg r = S[q=c][j=4g+r | 16+4g+r] ----
        f32x4 s0 = (f32x4){0.f,0.f,0.f,0.f};
        f32x4 s1 = (f32x4){0.f,0.f,0.f,0.f};
        __builtin_amdgcn_s_setprio(1);
        #pragma unroll
        for (int kk = 0; kk < 8; ++kk) {
            f16x8 b0 = *(const f16x8*)(kb + kk*2048        + c*64 + g*16);
            f16x8 b1 = *(const f16x8*)(kb + kk*2048 + 1024 + c*64 + g*16);
            s0 = __builtin_amdgcn_mfma_f32_16x16x32_f16(b0, qf[kk], s0, 0, 0, 0);
            s1 = __builtin_amdgcn_mfma_f32_16x16x32_f16(b1, qf[kk], s1, 0, 0, 0);
        }
        __builtin_amdgcn_s_setprio(0);

        asm volatile("s_waitcnt vmcnt(0)" ::: "memory");   // own V(t) landed
        __builtin_amdgcn_s_barrier();                      // V ready + K fully read
        if (more) stage_k(kv0 + 2*KVB);                    // overwrite K under SM/PV

        // ---- column mask: j = kv0 + 4g + r (s0), +16 (s1) ----
        const float NEG = -1e30f;
        if (kv0 + KVB > (int)Lb) {
            const int jb = kv0 + g*4;
            #pragma unroll
            for (int r = 0; r < 4; ++r) {
                if (jb + r >= Lb)      s0[r] = NEG;
                if (jb + 16 + r >= Lb) s1[r] = NEG;
            }
        }

        // ---- online softmax, row q=c: in-lane + 2 shuffles ----
        float tm = fmaxf(fmaxf(fmaxf(s0[0],s0[1]), fmaxf(s0[2],s0[3])),
                         fmaxf(fmaxf(s1[0],s1[1]), fmaxf(s1[2],s1[3])));
        tm = fmaxf(tm, __shfl_xor(tm, 16, 64));
        tm = fmaxf(tm, __shfl_xor(tm, 32, 64));
        if (__any(tm > m + 8.f)) {           // defer-max THR=8
            float mn = fmaxf(m, tm);
            float sc = __expf(m - mn);
            m = mn; l *= sc;
            float scr[4];
            #pragma unroll
            for (int r = 0; r < 4; ++r) scr[r] = bperm_f(g*4 + r, sc);
            #pragma unroll
            for (int dt = 0; dt < 16; ++dt) {
                o[dt][0]*=scr[0]; o[dt][1]*=scr[1]; o[dt][2]*=scr[2]; o[dt][3]*=scr[3];
            }
        }
        float p0[4], p1[4];
        #pragma unroll
        for (int r = 0; r < 4; ++r) {
            p0[r] = __expf(s0[r] - m);
            p1[r] = __expf(s1[r] - m);
        }
        float rs = ((p0[0]+p0[1]) + (p0[2]+p0[3])) + ((p1[0]+p1[1]) + (p1[2]+p1[3]));
        rs += __shfl_xor(rs, 16, 64);
        rs += __shfl_xor(rs, 32, 64);
        l += rs;

        // ---- P repack: write j=4g..4g+3 and 16+4g..+3, read j=8g..8g+7 ----
        f16x4 pa, pb;
        pa[0]=(f16)p0[0]; pa[1]=(f16)p0[1]; pa[2]=(f16)p0[2]; pa[3]=(f16)p0[3];
        pb[0]=(f16)p1[0]; pb[1]=(f16)p1[1]; pb[2]=(f16)p1[2]; pb[3]=(f16)p1[3];
        *(f16x4*)&pw[c*40 + 4*g]      = pa;
        *(f16x4*)&pw[c*40 + 16 + 4*g] = pb;
        f16x8 pf = *(const f16x8*)&pw[c*40 + 8*g];

        // ---- PV: O[16q x 256d], A=pf (P[q=c][j=8g+i]), B=vf ----
        __builtin_amdgcn_s_setprio(1);
        #pragma unroll
        for (int dt = 0; dt < 16; ++dt) {
            f16x8 vf = *(const f16x8*)(vb + dt*1024 + c*64 + g*16);
            o[dt] = __builtin_amdgcn_mfma_f32_16x16x32_f16(pf, vf, o[dt], 0, 0, 0);
        }
        __builtin_amdgcn_s_setprio(0);

        asm volatile("" ::: "memory");
        __builtin_amdgcn_s_barrier();                      // all done reading V(t)
        if (more) stage_v(kv0 + 2*KVB);
    }

    // ---- epilogue: normalized partial (f16) + per-row logsumexp (f32) ----
    float linv = 1.f / l;
    float inv[4];
    #pragma unroll
    for (int r = 0; r < 4; ++r) inv[r] = bperm_f(g*4 + r, linv);
    f16* op = Op + (size_t)h*XSZ + ((size_t)bsel*NN + (size_t)(qt*QB + w*16 + g*4))*ND + c;
    #pragma unroll
    for (int r = 0; r < 4; ++r) {
        #pragma unroll
        for (int dt = 0; dt < 16; ++dt)
            op[(size_t)r*ND + dt*16] = (f16)(o[dt][r] * inv[r]);
    }
    if (g == 0) {
        Sl[((size_t)(h*NB + bsel))*NN + (size_t)(qt*QB + w*16 + c)] = m + __logf(l);
    }
}

// ---------------- merge: out = (O1 w1 + O2 w2) / (w1 + w2) ------------------
__global__ __launch_bounds__(256)
void merge(const f16* __restrict__ Op, const float* __restrict__ Sl,
           const int* __restrict__ lenp, float* __restrict__ out)
{
    const int tid = threadIdx.x;
    const int rg  = blockIdx.x * 8 + (tid >> 5);   // global row 0..32767
    const int b   = rg >> 11;
    const int q   = rg & 2047;
    const int d0  = (tid & 31) * 8;

    const bool is64 = (lenp[1] == 0);
    const long long Lb = len_at(lenp, b, is64);

    const f16* p1 = Op + ((size_t)b*NN + q)*ND + d0;
    f16x8 a1 = *(const f16x8*)p1;
    float r[8];
    if (Lb <= KVB) {
        #pragma unroll
        for (int i = 0; i < 8; ++i) r[i] = (float)a1[i];
    } else {
        f16x8 a2 = *(const f16x8*)(p1 + XSZ);
        float s1 = Sl[(size_t)b*NN + q];
        float s2 = Sl[(size_t)(NB + b)*NN + q];
        float sm = fmaxf(s1, s2);
        float w1 = __expf(s1 - sm), w2 = __expf(s2 - sm);
        float dn = 1.f / (w1 + w2);
        w1 *= dn; w2 *= dn;
        #pragma unroll
        for (int i = 0; i < 8; ++i) r[i] = (float)a1[i]*w1 + (float)a2[i]*w2;
    }
    float* ob = out + ((size_t)b*NN + q)*ND + d0;
    *(float4*)ob       = (float4){r[0], r[1], r[2], r[3]};
    *(float4*)(ob + 4) = (float4){r[4], r[5], r[6], r[7]};
}

// ---------------- mid-tier (round-5 attn4, proven) --------------------------
__global__ __launch_bounds__(256, 2)
void attn4(const f16* __restrict__ Xh, const f16* __restrict__ Xt,
           const int* __restrict__ lenp, float* __restrict__ out)
{
    const int tid  = threadIdx.x;
    const int lane = tid & 63;
    const int w = tid >> 6;
    const int g = lane >> 4;
    const int c = lane & 15;

    const bool is64 = (lenp[1] == 0);
    long long Lv[NB];
    #pragma unroll
    for (int i = 0; i < NB; ++i) Lv[i] = len_at(lenp, i, is64);
    const int x = blockIdx.x & 7;
    const int k = blockIdx.x >> 3;
    const int wanted = (k < 32) ? x : (15 - x);
    const int qt = k & 31;
    int bsel = 0; long long Lb = 1;
    #pragma unroll
    for (int bb = 0; bb < NB; ++bb) {
        int rk = 0;
        #pragma unroll
        for (int b2 = 0; b2 < NB; ++b2)
            rk += (Lv[b2] > Lv[bb]) || (Lv[b2] == Lv[bb] && b2 < bb);
        if (rk == wanted) { bsel = bb; Lb = Lv[bb]; }
    }
    const int nt = (int)((Lb + KVB - 1) / KVB);

    __shared__ f16 Kl[2][8192];
    __shared__ f16 Vl[2][8192];
    __shared__ f16 Pl[4][16*36];

    const char* xhb = (const char*)(Xh + (size_t)bsel*NN*ND);
    const char* xtb = (const char*)(Xt + (size_t)bsel*ND*NN);

    f16x8 qf[8];
    {
        const char* qp = xhb + (size_t)(qt*QB + w*16 + c)*512 + g*16;
        #pragma unroll
        for (int kk = 0; kk < 8; ++kk) qf[kk] = *(const f16x8*)(qp + kk*64);
    }

    auto stage = [&](int buf, int kv0) {
        char* kb = (char*)&Kl[buf][0];
        char* vb = (char*)&Vl[buf][0];
        #pragma unroll
        for (int it = 0; it < 4; ++it) {
            int S  = it*256 + tid;
            int kk = S >> 7, j = (S >> 2) & 31, gg = S & 3;
            gll16(xhb + (size_t)(kv0 + j)*512 + kk*64 + gg*16, kb + S*16);
        }
        #pragma unroll
        for (int it = 0; it < 4; ++it) {
            int T  = it*256 + tid;
            int dt = T >> 6, cc = (T >> 2) & 15, gg = T & 3;
            gll16(xtb + (size_t)(dt*16 + cc)*4096 + (size_t)(kv0 + gg*8)*2, vb + T*16);
        }
    };

    f32x4 o[16];
    #pragma unroll
    for (int dt = 0; dt < 16; ++dt) o[dt] = (f32x4){0.f,0.f,0.f,0.f};
    float m[4] = {-INFINITY,-INFINITY,-INFINITY,-INFINITY};
    float l[4] = {0.f,0.f,0.f,0.f};

    f16* pw = &Pl[w][0];

    stage(0, 0);
    if (nt > 1) stage(1, KVB);

    for (int t = 0; t < nt; ++t) {
        const int kv0 = t * KVB;
        const int buf = t & 1;

        if (t + 1 < nt) { asm volatile("s_waitcnt vmcnt(8)" ::: "memory"); }
        else            { asm volatile("s_waitcnt vmcnt(0)" ::: "memory"); }
        __builtin_amdgcn_s_barrier();

        const char* kb = (const char*)&Kl[buf][0];
        const char* vb = (const char*)&Vl[buf][0];

        f32x4 s0 = (f32x4){0.f,0.f,0.f,0.f};
        f32x4 s1 = (f32x4){0.f,0.f,0.f,0.f};
        #pragma unroll
        for (int kk = 0; kk < 8; ++kk) {
            f16x8 b0 = *(const f16x8*)(kb + kk*2048        + c*64 + g*16);
            f16x8 b1 = *(const f16x8*)(kb + kk*2048 + 1024 + c*64 + g*16);
            s0 = __builtin_amdgcn_mfma_f32_16x16x32_f16(qf[kk], b0, s0, 0, 0, 0);
            s1 = __builtin_amdgcn_mfma_f32_16x16x32_f16(qf[kk], b1, s1, 0, 0, 0);
        }

        const float NEG = -1e30f;
        if (kv0 + c >= Lb)      { s0[0]=NEG; s0[1]=NEG; s0[2]=NEG; s0[3]=NEG; }
        if (kv0 + 16 + c >= Lb) { s1[0]=NEG; s1[1]=NEG; s1[2]=NEG; s1[3]=NEG; }

        float mx[4], mn[4], sc[4], p0[4], p1[4], rs[4];
        #pragma unroll
        for (int r = 0; r < 4; ++r) mx[r] = fmaxf(s0[r], s1[r]);
        #pragma unroll
        for (int off = 8; off >= 1; off >>= 1) {
            #pragma unroll
            for (int r = 0; r < 4; ++r)
                mx[r] = fmaxf(mx[r], __shfl_xor(mx[r], off, 64));
        }
        #pragma unroll
        for (int r = 0; r < 4; ++r) {
            mn[r] = fmaxf(m[r], mx[r]);
            sc[r] = __expf(m[r] - mn[r]);
            p0[r] = __expf(s0[r] - mn[r]);
            p1[r] = __expf(s1[r] - mn[r]);
            rs[r] = p0[r] + p1[r];
        }
        #pragma unroll
        for (int off = 8; off >= 1; off >>= 1) {
            #pragma unroll
            for (int r = 0; r < 4; ++r)
                rs[r] += __shfl_xor(rs[r], off, 64);
        }
        bool chg = (sc[0]!=1.f) | (sc[1]!=1.f) | (sc[2]!=1.f) | (sc[3]!=1.f);
        if (__any(chg)) {
            #pragma unroll
            for (int dt = 0; dt < 16; ++dt) {
                o[dt][0]*=sc[0]; o[dt][1]*=sc[1]; o[dt][2]*=sc[2]; o[dt][3]*=sc[3];
            }
        }
        #pragma unroll
        for (int r = 0; r < 4; ++r) { l[r] = l[r]*sc[r] + rs[r]; m[r] = mn[r]; }

        #pragma unroll
        for (int r = 0; r < 4; ++r) {
            pw[(g*4+r)*36 + c]      = (f16)p0[r];
            pw[(g*4+r)*36 + 16 + c] = (f16)p1[r];
        }
        union { f16x4 hh[2]; f16x8 v; } pu;
        pu.hh[0] = *(const f16x4*)(pw + c*36 + g*8);
        pu.hh[1] = *(const f16x4*)(pw + c*36 + g*8 + 4);
        f16x8 pf = pu.v;

        #pragma unroll
        for (int dt = 0; dt < 16; ++dt) {
            f16x8 vf = *(const f16x8*)(vb + dt*1024 + c*64 + g*16);
            o[dt] = __builtin_amdgcn_mfma_f32_16x16x32_f16(pf, vf, o[dt], 0, 0, 0);
        }

        __builtin_amdgcn_s_barrier();
        if (t + 2 < nt) stage(buf, kv0 + 2*KVB);
    }

    float inv[4];
    #pragma unroll
    for (int r = 0; r < 4; ++r) inv[r] = 1.0f / l[r];
    float* ob = out + ((size_t)bsel*NN + (size_t)(qt*QB + w*16 + g*4))*ND + c;
    #pragma unroll
    for (int r = 0; r < 4; ++r) {
        #pragma unroll
        for (int dt = 0; dt < 16; ++dt)
            ob[(size_t)r*ND + dt*16] = o[dt][r] * inv[r];
    }
}

// ---------------- lowest tier (no workspace) --------------------------------
__global__ __launch_bounds__(256, 2)
void attn_fb(const float* __restrict__ X,
             const int* __restrict__ lenp,
             float* __restrict__ out)
{
    const int b   = blockIdx.y;
    const int qt  = blockIdx.x;
    const int tid = threadIdx.x;
    const int lane = tid & 63;
    const int w = tid >> 6;
    const int g = lane >> 4;
    const int c = lane & 15;

    const bool is64 = (lenp[1] == 0);
    const long long Lb = len_at(lenp, b, is64);

    __shared__ f16 Kl[KVB][264];
    __shared__ f16 Vt2[ND][40];
    __shared__ f16 Pl[4][16][40];

    const float* Xb = X + (size_t)b * NN * ND;

    f16x8 qf[8];
    {
        const float* qp = Xb + (size_t)(qt*64 + w*16 + c) * ND + g*8;
        #pragma unroll
        for (int kk = 0; kk < 8; ++kk) {
            float4 a = *(const float4*)(qp + kk*32);
            float4 d = *(const float4*)(qp + kk*32 + 4);
            f16x8 v;
            v[0]=(f16)a.x; v[1]=(f16)a.y; v[2]=(f16)a.z; v[3]=(f16)a.w;
            v[4]=(f16)d.x; v[5]=(f16)d.y; v[6]=(f16)d.z; v[7]=(f16)d.w;
            qf[kk] = v;
        }
    }

    f32x4 o[16];
    #pragma unroll
    for (int dt = 0; dt < 16; ++dt) o[dt] = (f32x4){0.f,0.f,0.f,0.f};
    float m[4] = {-INFINITY,-INFINITY,-INFINITY,-INFINITY};
    float lr[4] = {0.f,0.f,0.f,0.f};

    const int ntiles = (int)((Lb + KVB - 1) / KVB);
    for (int t = 0; t < ntiles; ++t) {
        const int kv0 = t * KVB;
        __syncthreads();
        #pragma unroll
        for (int it = 0; it < 8; ++it) {
            int idx4 = it*256 + tid;
            int row  = idx4 >> 6;
            int c4   = idx4 & 63;
            float4 v = *(const float4*)(Xb + (size_t)(kv0 + row)*ND + c4*4);
            f16x4 hh; hh[0]=(f16)v.x; hh[1]=(f16)v.y; hh[2]=(f16)v.z; hh[3]=(f16)v.w;
            *(f16x4*)&Kl[row][c4*4] = hh;
        }
        {
            const float* cp = Xb + (size_t)kv0*ND + tid;
            #pragma unroll
            for (int kq = 0; kq < 8; ++kq) {
                f16x4 hh;
                #pragma unroll
                for (int u = 0; u < 4; ++u) hh[u] = (f16)cp[(size_t)(kq*4+u)*ND];
                *(f16x4*)&Vt2[tid][kq*4] = hh;
            }
        }
        __syncthreads();

        f32x4 s0 = (f32x4){0.f,0.f,0.f,0.f};
        f32x4 s1 = (f32x4){0.f,0.f,0.f,0.f};
        #pragma unroll
        for (int kk = 0; kk < 8; ++kk) {
            f16x8 b0 = *(const f16x8*)&Kl[c     ][kk*32 + g*8];
            f16x8 b1 = *(const f16x8*)&Kl[16 + c][kk*32 + g*8];
            s0 = __builtin_amdgcn_mfma_f32_16x16x32_f16(qf[kk], b0, s0, 0, 0, 0);
            s1 = __builtin_amdgcn_mfma_f32_16x16x32_f16(qf[kk], b1, s1, 0, 0, 0);
        }

        const float NEG = -1e30f;
        if (kv0 + c >= Lb)      { s0[0]=NEG; s0[1]=NEG; s0[2]=NEG; s0[3]=NEG; }
        if (kv0 + 16 + c >= Lb) { s1[0]=NEG; s1[1]=NEG; s1[2]=NEG; s1[3]=NEG; }

        float mx[4], mn[4], sc[4], p0[4], p1[4], rs[4];
        #pragma unroll
        for (int r = 0; r < 4; ++r) mx[r] = fmaxf(s0[r], s1[r]);
        #pragma unroll
        for (int off = 8; off >= 1; off >>= 1) {
            #pragma unroll
            for (int r = 0; r < 4; ++r)
                mx[r] = fmaxf(mx[r], __shfl_xor(mx[r], off, 64));
        }
        #pragma unroll
        for (int r = 0; r < 4; ++r) {
            mn[r] = fmaxf(m[r], mx[r]);
            sc[r] = __expf(m[r] - mn[r]);
            p0[r] = __expf(s0[r] - mn[r]);
            p1[r] = __expf(s1[r] - mn[r]);
            rs[r] = p0[r] + p1[r];
        }
        #pragma unroll
        for (int off = 8; off >= 1; off >>= 1) {
            #pragma unroll
            for (int r = 0; r < 4; ++r)
                rs[r] += __shfl_xor(rs[r], off, 64);
        }
        bool chg = (sc[0]!=1.f) | (sc[1]!=1.f) | (sc[2]!=1.f) | (sc[3]!=1.f);
        if (__any(chg)) {
            #pragma unroll
            for (int dt = 0; dt < 16; ++dt) {
                o[dt][0]*=sc[0]; o[dt][1]*=sc[1]; o[dt][2]*=sc[2]; o[dt][3]*=sc[3];
            }
        }
        #pragma unroll
        for (int r = 0; r < 4; ++r) { lr[r] = lr[r]*sc[r] + rs[r]; m[r] = mn[r]; }

        #pragma unroll
        for (int r = 0; r < 4; ++r) {
            Pl[w][g*4+r][c]      = (f16)p0[r];
            Pl[w][g*4+r][16 + c] = (f16)p1[r];
        }
        f16x8 pf = *(const f16x8*)&Pl[w][c][g*8];

        #pragma unroll
        for (int dt = 0; dt < 16; ++dt) {
            f16x8 vf = *(const f16x8*)&Vt2[dt*16 + c][g*8];
            o[dt] = __builtin_amdgcn_mfma_f32_16x16x32_f16(pf, vf, o[dt], 0, 0, 0);
        }
    }

    float inv[4];
    #pragma unroll
    for (int r = 0; r < 4; ++r) inv[r] = 1.0f / lr[r];
    float* ob = out + ((size_t)b*NN + (size_t)(qt*64 + w*16 + g*4))*ND + c;
    #pragma unroll
    for (int r = 0; r < 4; ++r) {
        #pragma unroll
        for (int dt = 0; dt < 16; ++dt)
            ob[(size_t)r*ND + dt*16] = o[dt][r] * inv[r];
    }
}

extern "C" void kernel_launch(void* const* d_in, const int* in_sizes, int n_in,
                              void* d_out, int out_size, void* d_ws, size_t ws_size,
                              hipStream_t stream) {
    const float* X    = (const float*)d_in[0];
    const int*   lenp = (const int*)d_in[1];
    float*       out  = (float*)d_out;

    const size_t need_base  = XSZ * 2 * 2;                    // Xh + Xt (f16)
    const size_t need_split = need_base + XSZ * 2 * 2         // + Op[2] (f16)
                              + (size_t)2 * NB * NN * 4;      // + Sl (f32)
    if (ws_size >= need_split) {
        f16* Xh = (f16*)d_ws;
        f16* Xt = Xh + XSZ;
        f16* Op = Xt + XSZ;
        float* Sl = (float*)(Op + 2*XSZ);
        hipLaunchKernelGGL(prep, dim3(NN/64, ND/64, NB), dim3(256), 0, stream, X, Xh, Xt);
        hipLaunchKernelGGL(attn11, dim3(1024), dim3(256), 0, stream, Xh, Xt, lenp, Op, Sl);
        hipLaunchKernelGGL(merge, dim3(NB*NN/8), dim3(256), 0, stream, Op, Sl, lenp, out);
    } else if (ws_size >= need_base) {
        f16* Xh = (f16*)d_ws;
        f16* Xt = Xh + XSZ;
        hipLaunchKernelGGL(prep, dim3(NN/64, ND/64, NB), dim3(256), 0, stream, X, Xh, Xt);
        hipLaunchKernelGGL(attn4, dim3(512), dim3(256), 0, stream, Xh, Xt, lenp, out);
    } else {
        hipLaunchKernelGGL(attn_fb, dim3(NN/64, NB), dim3(256), 0, stream, X, lenp, out);
    }
}